// Round 16
// baseline (15.015 us; speedup 1.0000x reference)
//
#include <hip/hip_runtime.h>

#define BB 256
#define PP 64
#define LL 16
#define DD 64
#define IMGF 512

__device__ __forceinline__ float wred_sum(float v) {
#pragma unroll
    for (int off = 32; off > 0; off >>= 1) v += __shfl_xor(v, off, 64);
    return v;
}

// sum across a 16-lane group (groups aligned on 16-lane boundaries)
__device__ __forceinline__ float gred_sum16(float v) {
    v += __shfl_xor(v, 1, 64);
    v += __shfl_xor(v, 2, 64);
    v += __shfl_xor(v, 4, 64);
    v += __shfl_xor(v, 8, 64);
    return v;
}

__device__ __forceinline__ float dot4(float4 a, float4 b) {
    return a.x * b.x + a.y * b.y + a.z * b.z + a.w * b.w;
}

// 1/max(sqrt(n),1e-12) ~= rsqrt(max(n,1e-24)): single v_rsq_f32, ~2ulp.
__device__ __forceinline__ float rnorm_fast(float n) {
    return rsqrtf(fmaxf(n, 1e-24f));
}

// R14 structure, 3 barriers (was 4): after bar2 every wave recomputes qv/rv
// in-register (redundant wred_sums hidden under gather latency), weight term
// computed inline at path-phase end via shfl relayout -- no qf/rf LDS
// round-trip, no separate weight barrier. Row norms via 16->1 reduce-scatter;
// i2/i3/i4 via t[k] factorization; masked gathers redirect to row 0.
__launch_bounds__(1024, 1)
__global__ void k_fused(const int* __restrict__ qry_id, const int* __restrict__ res_id,
                        const int* __restrict__ path, const int* __restrict__ mask,
                        const float* __restrict__ img, const float* __restrict__ Ww,
                        const float* __restrict__ Wb,
                        const float* __restrict__ meta,
                        const float* __restrict__ hw, const float* __restrict__ hb,
                        const float* __restrict__ p1w, const float* __restrict__ p1b,
                        const float* __restrict__ p2w, const float* __restrict__ p2b,
                        float* __restrict__ out) {
    __shared__ float fq[IMGF], fr[IMGF];     // staged image feature rows
    __shared__ float pq_row[DD], pr_row[DD]; // GEMV row dots (pre-norm)
    __shared__ float pr_sh[PP][DD];          // path_res
    __shared__ float weight_sh[PP];
    __shared__ float wsh[PP];

    int b = blockIdx.x;
    int tid = threadIdx.x;
    int lane = tid & 63;
    int wv = tid >> 6;        // 0..15
    int g = lane >> 4;        // 16-lane group in wave: 0..3
    int j = lane & 15;        // lane within group
    int p = wv * 4 + g;       // this group's path index

    // ---- load this group's path indices+mask (coalesced, 1 int/lane) ----
    int packed;
    {
        int pj = path[(b * PP + p) * LL + j];
        int mj = mask[(b * PP + p) * LL + j];
        packed = pj | (mj << 16);     // idx < 50000 < 65536
    }

    // ---- stage the two gathered image-feature rows (coalesced) ----
    {
        int qid = qry_id[b], rid = res_id[b];
        if (tid < IMGF) fq[tid] = img[(long long)qid * IMGF + tid];
        else            fr[tid - IMGF] = img[(long long)rid * IMGF + (tid - IMGF)];
    }
    __syncthreads();                         // bar1

    // ---- GEMV: group (wv,g) owns output row p; contiguous float4 striding ----
    {
        const float4* wr = (const float4*)(Ww + p * IMGF);
        const float4* q4p = (const float4*)fq;
        const float4* r4p = (const float4*)fr;
        float aq = 0.f, ar = 0.f;
#pragma unroll
        for (int i = 0; i < 8; ++i) {
            float4 w4 = wr[i * 16 + j];               // group: 256B contiguous
            aq += dot4(w4, q4p[i * 16 + j]);
            ar += dot4(w4, r4p[i * 16 + j]);
        }
        aq = gred_sum16(aq);
        ar = gred_sum16(ar);
        if (j == 0) { pq_row[p] = aq; pr_row[p] = ar; }
    }
    __syncthreads();                         // bar2

    // ---- path: issue all 16 gathers FIRST ----
    float4 v[16];
#pragma unroll
    for (int l = 0; l < LL; ++l) {
        int im = __shfl(packed, (lane & 48) | l, 64);
        int idx = (im >> 16) ? (im & 0xFFFF) : 0;   // masked -> row 0 (L1-hot)
        v[l] = *(const float4*)(meta + idx * DD + 4 * j);
    }

    // ---- redundant per-wave qv/rv (hidden under gather latency) ----
    float qv, rv;
    {
        float accq = Wb[lane] + pq_row[lane];
        float accr = Wb[lane] + pr_row[lane];
        qv = accq * rnorm_fast(wred_sum(accq * accq));
        rv = accr * rnorm_fast(wred_sum(accr * accr));
    }

    // ---- consume gathers: per-lane partial sumsq per row ----
    float ss[16];
#pragma unroll
    for (int l = 0; l < LL; ++l) ss[l] = dot4(v[l], v[l]);

    // ---- reduce-scatter across the 16-lane group: lane j <- total of row j ----
    float s8[8];
    {
        bool hi = (lane & 8) != 0;
#pragma unroll
        for (int i = 0; i < 8; ++i) {
            float snd = hi ? ss[i] : ss[i + 8];
            float kp  = hi ? ss[i + 8] : ss[i];
            s8[i] = kp + __shfl_xor(snd, 8, 64);
        }
    }
    float s4[4];
    {
        bool hi = (lane & 4) != 0;
#pragma unroll
        for (int i = 0; i < 4; ++i) {
            float snd = hi ? s8[i] : s8[i + 4];
            float kp  = hi ? s8[i + 4] : s8[i];
            s4[i] = kp + __shfl_xor(snd, 4, 64);
        }
    }
    float s2[2];
    {
        bool hi = (lane & 2) != 0;
#pragma unroll
        for (int i = 0; i < 2; ++i) {
            float snd = hi ? s4[i] : s4[i + 2];
            float kp  = hi ? s4[i + 2] : s4[i];
            s2[i] = kp + __shfl_xor(snd, 2, 64);
        }
    }
    float S;
    {
        bool hi = (lane & 1) != 0;
        float snd = hi ? s2[0] : s2[1];
        float kp  = hi ? s2[1] : s2[0];
        S = kp + __shfl_xor(snd, 1, 64);
    }
    // lane j now holds ||row j||^2 of its group; its own packed IS row j
    float mr_j = (float)(packed >> 16) * rnorm_fast(S);

    // ---- pm[k] = norm'd row 2k + norm'd row 2k+1 (pair-broadcast mr) ----
    float4 pm[8];
#pragma unroll
    for (int k = 0; k < 8; ++k) {
        float mr0 = __shfl(mr_j, (lane & 48) | (2 * k), 64);
        float mr1 = __shfl(mr_j, (lane & 48) | (2 * k + 1), 64);
        pm[k].x = v[2 * k].x * mr0 + v[2 * k + 1].x * mr1;
        pm[k].y = v[2 * k].y * mr0 + v[2 * k + 1].y * mr1;
        pm[k].z = v[2 * k].z * mr0 + v[2 * k + 1].z * mr1;
        pm[k].w = v[2 * k].w * mr0 + v[2 * k + 1].w * mr1;
    }

    // ---- i2/i3/i4 via t[k] = pm[k]*pm[k+1] factorization ----
    float4 t[7];
#pragma unroll
    for (int k = 0; k < 7; ++k) {
        t[k].x = pm[k].x * pm[k + 1].x;
        t[k].y = pm[k].y * pm[k + 1].y;
        t[k].z = pm[k].z * pm[k + 1].z;
        t[k].w = pm[k].w * pm[k + 1].w;
    }
    float4 a2 = t[0];
#pragma unroll
    for (int k = 1; k < 7; ++k) {
        a2.x += t[k].x; a2.y += t[k].y; a2.z += t[k].z; a2.w += t[k].w;
    }
    float4 a3 = make_float4(0.f, 0.f, 0.f, 0.f);
#pragma unroll
    for (int k = 0; k < 6; ++k) {
        a3.x += t[k].x * pm[k + 2].x;
        a3.y += t[k].y * pm[k + 2].y;
        a3.z += t[k].z * pm[k + 2].z;
        a3.w += t[k].w * pm[k + 2].w;
    }
    float4 a4 = make_float4(0.f, 0.f, 0.f, 0.f);
#pragma unroll
    for (int k = 0; k < 5; ++k) {
        a4.x += t[k].x * t[k + 2].x;
        a4.y += t[k].y * t[k + 2].y;
        a4.z += t[k].z * t[k + 2].z;
        a4.w += t[k].w * t[k + 2].w;
    }
    a2.x *= (1.0f / 7.0f); a2.y *= (1.0f / 7.0f); a2.z *= (1.0f / 7.0f); a2.w *= (1.0f / 7.0f);
    a3.x *= (1.0f / 6.0f); a3.y *= (1.0f / 6.0f); a3.z *= (1.0f / 6.0f); a3.w *= (1.0f / 6.0f);
    a4.x *= (1.0f / 5.0f); a4.y *= (1.0f / 5.0f); a4.z *= (1.0f / 5.0f); a4.w *= (1.0f / 5.0f);
    float i2n = rnorm_fast(gred_sum16(dot4(a2, a2)));
    float i3n = rnorm_fast(gred_sum16(dot4(a3, a3)));
    float i4n = rnorm_fast(gred_sum16(dot4(a4, a4)));
    float4 pr;
    pr.x = (a2.x * i2n + a3.x * i3n + a4.x * i4n) * (1.0f / 3.0f);
    pr.y = (a2.y * i2n + a3.y * i3n + a4.y * i4n) * (1.0f / 3.0f);
    pr.z = (a2.z * i2n + a3.z * i3n + a4.z * i4n) * (1.0f / 3.0f);
    pr.w = (a2.w * i2n + a3.w * i3n + a4.w * i4n) * (1.0f / 3.0f);
    ((float4*)pr_sh[p])[j] = pr;

    // ---- weight inline: relayout qv/rv to group float4 via 8 shfls ----
    {
        float4 q4, r4;
        q4.x = __shfl(qv, 4 * j, 64);     r4.x = __shfl(rv, 4 * j, 64);
        q4.y = __shfl(qv, 4 * j + 1, 64); r4.y = __shfl(rv, 4 * j + 1, 64);
        q4.z = __shfl(qv, 4 * j + 2, 64); r4.z = __shfl(rv, 4 * j + 2, 64);
        q4.w = __shfl(qv, 4 * j + 3, 64); r4.w = __shfl(rv, 4 * j + 3, 64);
        float4 h0 = ((const float4*)hw)[j];
        float4 h1 = ((const float4*)(hw + DD))[j];
        float w = -(q4.x - r4.x) * pr.x * h0.x + (q4.x * r4.x) * h1.x
                  - (q4.y - r4.y) * pr.y * h0.y + (q4.y * r4.y) * h1.y
                  - (q4.z - r4.z) * pr.z * h0.z + (q4.z * r4.z) * h1.z
                  - (q4.w - r4.w) * pr.w * h0.w + (q4.w * r4.w) * h1.w;
        w = gred_sum16(w);
        if (j == 0) weight_sh[p] = w;
    }
    __syncthreads();                         // bar3: pr_sh + weight_sh done

    // ---- finale: wave 0 does softmax over P, pooled, scores ----
    if (wv == 0) {
        float wt = (weight_sh[lane] + hb[0]) * 5.0f;   // /0.2
        float mx = wt;
#pragma unroll
        for (int off = 32; off > 0; off >>= 1) mx = fmaxf(mx, __shfl_xor(mx, off, 64));
        float e = __expf(wt - mx);
        float wn = e / wred_sum(e);
        wsh[lane] = wn;
        float pooled = 0.f;
#pragma unroll 8
        for (int pp2 = 0; pp2 < PP; ++pp2) pooled += pr_sh[pp2][lane] * wsh[pp2];
        float s1 = wred_sum(qv * rv * p1w[lane]);
        float s2 = wred_sum((rv - qv) * pooled * p2w[lane]);
        if (lane == 0) out[b] = (s1 + p1b[0]) + 5.0f * (s2 + p2b[0]);
    }
}

extern "C" void kernel_launch(void* const* d_in, const int* in_sizes, int n_in,
                              void* d_out, int out_size, void* d_ws, size_t ws_size,
                              hipStream_t stream) {
    const int*   qry_id = (const int*)d_in[0];
    const int*   res_id = (const int*)d_in[1];
    const int*   path   = (const int*)d_in[2];
    const int*   mask   = (const int*)d_in[3];
    const float* img    = (const float*)d_in[4];
    const float* Ww     = (const float*)d_in[5];
    const float* Wb     = (const float*)d_in[6];
    const float* meta   = (const float*)d_in[7];
    const float* hw     = (const float*)d_in[8];
    const float* hb     = (const float*)d_in[9];
    const float* p1w    = (const float*)d_in[10];
    const float* p1b    = (const float*)d_in[11];
    const float* p2w    = (const float*)d_in[12];
    const float* p2b    = (const float*)d_in[13];

    float* out = (float*)d_out;

    hipLaunchKernelGGL(k_fused, dim3(BB), dim3(1024), 0, stream,
                       qry_id, res_id, path, mask, img, Ww, Wb, meta,
                       hw, hb, p1w, p1b, p2w, p2b, out);
}

// Round 18
// 13.299 us; speedup vs baseline: 1.1291x; 1.1291x over previous
//
#include <hip/hip_runtime.h>

#define BB 256
#define PP 64
#define LL 16
#define DD 64
#define IMGF 512

// ---- fast cross-lane primitives ----
// xor1/xor2: quad-internal -> DPP quad_perm (VALU speed, no lgkm wait)
__device__ __forceinline__ float dxor1(float v) {
    return __int_as_float(__builtin_amdgcn_mov_dpp(__float_as_int(v), 0xB1, 0xF, 0xF, true));
}
__device__ __forceinline__ float dxor2(float v) {
    return __int_as_float(__builtin_amdgcn_mov_dpp(__float_as_int(v), 0x4E, 0xF, 0xF, true));
}
// xor4/8/16: single ds_swizzle (BitMode), no index VALU
__device__ __forceinline__ float sxor4(float v) {
    return __int_as_float(__builtin_amdgcn_ds_swizzle(__float_as_int(v), 0x101F));
}
__device__ __forceinline__ float sxor8(float v) {
    return __int_as_float(__builtin_amdgcn_ds_swizzle(__float_as_int(v), 0x201F));
}
__device__ __forceinline__ float sxor16(float v) {
    return __int_as_float(__builtin_amdgcn_ds_swizzle(__float_as_int(v), 0x401F));
}

__device__ __forceinline__ float wred_sum(float v) {
    v += __shfl_xor(v, 32, 64);
    v += sxor16(v);
    v += sxor8(v);
    v += sxor4(v);
    v += dxor2(v);
    v += dxor1(v);
    return v;
}
__device__ __forceinline__ float wred_max(float v) {
    v = fmaxf(v, __shfl_xor(v, 32, 64));
    v = fmaxf(v, sxor16(v));
    v = fmaxf(v, sxor8(v));
    v = fmaxf(v, sxor4(v));
    v = fmaxf(v, dxor2(v));
    v = fmaxf(v, dxor1(v));
    return v;
}
// sum across 16-lane group
__device__ __forceinline__ float gred_sum16(float v) {
    v += dxor1(v);
    v += dxor2(v);
    v += sxor4(v);
    v += sxor8(v);
    return v;
}

__device__ __forceinline__ float dot4(float4 a, float4 b) {
    return a.x * b.x + a.y * b.y + a.z * b.z + a.w * b.w;
}

// 1/max(sqrt(n),1e-12) ~= rsqrt(max(n,1e-24)): single v_rsq_f32, ~2ulp.
__device__ __forceinline__ float rnorm_fast(float n) {
    return rsqrtf(fmaxf(n, 1e-24f));
}

// R14 structure (best known: staged GEMV, gathers post-bar2, 4 barriers)
// + DPP/swizzle reductions, mean-scaling cancellation, fused finale.
__launch_bounds__(1024, 1)
__global__ void k_fused(const int* __restrict__ qry_id, const int* __restrict__ res_id,
                        const int* __restrict__ path, const int* __restrict__ mask,
                        const float* __restrict__ img, const float* __restrict__ Ww,
                        const float* __restrict__ Wb,
                        const float* __restrict__ meta,
                        const float* __restrict__ hw, const float* __restrict__ hb,
                        const float* __restrict__ p1w, const float* __restrict__ p1b,
                        const float* __restrict__ p2w, const float* __restrict__ p2b,
                        float* __restrict__ out) {
    __shared__ float fq[IMGF], fr[IMGF];     // staged image feature rows
    __shared__ float pq_row[DD], pr_row[DD]; // GEMV row dots (pre-norm)
    __shared__ float qf[DD], rf[DD];         // normalized features
    __shared__ float pr_sh[PP][DD];          // path_res
    __shared__ float weight_sh[PP];
    __shared__ float wsh[PP];

    int b = blockIdx.x;
    int tid = threadIdx.x;
    int lane = tid & 63;
    int wv = tid >> 6;        // 0..15
    int g = lane >> 4;        // 16-lane group in wave: 0..3
    int j = lane & 15;        // lane within group
    int p = wv * 4 + g;       // this group's path index

    // ---- load this group's path indices+mask (coalesced, 1 int/lane) ----
    int packed;
    {
        int pj = path[(b * PP + p) * LL + j];
        int mj = mask[(b * PP + p) * LL + j];
        packed = pj | (mj << 16);     // idx < 50000 < 65536
    }

    // ---- stage the two gathered image-feature rows (coalesced) ----
    {
        int qid = qry_id[b], rid = res_id[b];
        if (tid < IMGF) fq[tid] = img[(long long)qid * IMGF + tid];
        else            fr[tid - IMGF] = img[(long long)rid * IMGF + (tid - IMGF)];
    }
    __syncthreads();                         // bar1

    // ---- GEMV: group (wv,g) owns output row p; contiguous float4 striding ----
    {
        const float4* wr = (const float4*)(Ww + p * IMGF);
        const float4* q4p = (const float4*)fq;
        const float4* r4p = (const float4*)fr;
        float aq = 0.f, ar = 0.f;
#pragma unroll
        for (int i = 0; i < 8; ++i) {
            float4 w4 = wr[i * 16 + j];               // group: 256B contiguous
            aq += dot4(w4, q4p[i * 16 + j]);
            ar += dot4(w4, r4p[i * 16 + j]);
        }
        aq = gred_sum16(aq);
        ar = gred_sum16(ar);
        if (j == 0) { pq_row[p] = aq; pr_row[p] = ar; }
    }
    __syncthreads();                         // bar2
    if (wv < 2) {                      // finish norms while others issue gathers
        float acc = Wb[lane] + (wv ? pr_row[lane] : pq_row[lane]);
        float n = wred_sum(acc * acc);
        float val = acc * rnorm_fast(n);
        (wv ? rf : qf)[lane] = val;
    }

    // ---- path: issue all 16 gathers; per-lane partial sumsq per row ----
    float4 v[16];
#pragma unroll
    for (int l = 0; l < LL; ++l) {
        int im = __shfl(packed, (lane & 48) | l, 64);
        int idx = (im >> 16) ? (im & 0xFFFF) : 0;   // masked -> row 0 (L1-hot)
        v[l] = *(const float4*)(meta + idx * DD + 4 * j);
    }
    float ss[16];
#pragma unroll
    for (int l = 0; l < LL; ++l) ss[l] = dot4(v[l], v[l]);

    // ---- reduce-scatter across the 16-lane group: lane j <- total of row j ----
    float s8[8];
    {
        bool hi = (lane & 8) != 0;
#pragma unroll
        for (int i = 0; i < 8; ++i) {
            float snd = hi ? ss[i] : ss[i + 8];
            float kp  = hi ? ss[i + 8] : ss[i];
            s8[i] = kp + sxor8(snd);
        }
    }
    float s4[4];
    {
        bool hi = (lane & 4) != 0;
#pragma unroll
        for (int i = 0; i < 4; ++i) {
            float snd = hi ? s8[i] : s8[i + 4];
            float kp  = hi ? s8[i + 4] : s8[i];
            s4[i] = kp + sxor4(snd);
        }
    }
    float s2[2];
    {
        bool hi = (lane & 2) != 0;
#pragma unroll
        for (int i = 0; i < 2; ++i) {
            float snd = hi ? s4[i] : s4[i + 2];
            float kp  = hi ? s4[i + 2] : s4[i];
            s2[i] = kp + dxor2(snd);
        }
    }
    float S;
    {
        bool hi = (lane & 1) != 0;
        float snd = hi ? s2[0] : s2[1];
        float kp  = hi ? s2[1] : s2[0];
        S = kp + dxor1(snd);
    }
    // lane j now holds ||row j||^2 of its group; its own packed IS row j
    float mr_j = (float)(packed >> 16) * rnorm_fast(S);

    // ---- pm[k] = norm'd row 2k + norm'd row 2k+1 (pair-broadcast mr) ----
    float4 pm[8];
#pragma unroll
    for (int k = 0; k < 8; ++k) {
        float mr0 = __shfl(mr_j, (lane & 48) | (2 * k), 64);
        float mr1 = __shfl(mr_j, (lane & 48) | (2 * k + 1), 64);
        pm[k].x = v[2 * k].x * mr0 + v[2 * k + 1].x * mr1;
        pm[k].y = v[2 * k].y * mr0 + v[2 * k + 1].y * mr1;
        pm[k].z = v[2 * k].z * mr0 + v[2 * k + 1].z * mr1;
        pm[k].w = v[2 * k].w * mr0 + v[2 * k + 1].w * mr1;
    }

    // ---- i2/i3/i4 via t[k] = pm[k]*pm[k+1]; mean-scalings cancel in l2norm ----
    float4 t[7];
#pragma unroll
    for (int k = 0; k < 7; ++k) {
        t[k].x = pm[k].x * pm[k + 1].x;
        t[k].y = pm[k].y * pm[k + 1].y;
        t[k].z = pm[k].z * pm[k + 1].z;
        t[k].w = pm[k].w * pm[k + 1].w;
    }
    float4 a2 = t[0];
#pragma unroll
    for (int k = 1; k < 7; ++k) {
        a2.x += t[k].x; a2.y += t[k].y; a2.z += t[k].z; a2.w += t[k].w;
    }
    float4 a3 = make_float4(0.f, 0.f, 0.f, 0.f);
#pragma unroll
    for (int k = 0; k < 6; ++k) {
        a3.x += t[k].x * pm[k + 2].x;
        a3.y += t[k].y * pm[k + 2].y;
        a3.z += t[k].z * pm[k + 2].z;
        a3.w += t[k].w * pm[k + 2].w;
    }
    float4 a4 = make_float4(0.f, 0.f, 0.f, 0.f);
#pragma unroll
    for (int k = 0; k < 5; ++k) {
        a4.x += t[k].x * t[k + 2].x;
        a4.y += t[k].y * t[k + 2].y;
        a4.z += t[k].z * t[k + 2].z;
        a4.w += t[k].w * t[k + 2].w;
    }
    float i2n = rnorm_fast(gred_sum16(dot4(a2, a2)));
    float i3n = rnorm_fast(gred_sum16(dot4(a3, a3)));
    float i4n = rnorm_fast(gred_sum16(dot4(a4, a4)));
    float4 pr;
    pr.x = (a2.x * i2n + a3.x * i3n + a4.x * i4n) * (1.0f / 3.0f);
    pr.y = (a2.y * i2n + a3.y * i3n + a4.y * i4n) * (1.0f / 3.0f);
    pr.z = (a2.z * i2n + a3.z * i3n + a4.z * i4n) * (1.0f / 3.0f);
    pr.w = (a2.w * i2n + a3.w * i3n + a4.w * i4n) * (1.0f / 3.0f);
    ((float4*)pr_sh[p])[j] = pr;
    __syncthreads();   // bar3: qf/rf + pr_sh done

    {
        float4 q4 = ((const float4*)qf)[j];
        float4 r4 = ((const float4*)rf)[j];
        float4 h0 = ((const float4*)hw)[j];
        float4 h1 = ((const float4*)(hw + DD))[j];
        float w = -(q4.x - r4.x) * pr.x * h0.x + (q4.x * r4.x) * h1.x
                  - (q4.y - r4.y) * pr.y * h0.y + (q4.y * r4.y) * h1.y
                  - (q4.z - r4.z) * pr.z * h0.z + (q4.z * r4.z) * h1.z
                  - (q4.w - r4.w) * pr.w * h0.w + (q4.w * r4.w) * h1.w;
        w = gred_sum16(w);
        if (j == 0) weight_sh[p] = w;
    }
    __syncthreads();                         // bar4

    // ---- finale: wave 0 does softmax over P, pooled, scores ----
    if (wv == 0) {
        float wt = (weight_sh[lane] + hb[0]) * 5.0f;   // /0.2
        float mx = wred_max(wt);
        float e = __expf(wt - mx);
        float wn = e / wred_sum(e);
        wsh[lane] = wn;
        float pl0 = 0.f, pl1 = 0.f, pl2 = 0.f, pl3 = 0.f;
#pragma unroll 4
        for (int q = 0; q < PP; q += 4) {
            pl0 += pr_sh[q][lane] * wsh[q];
            pl1 += pr_sh[q + 1][lane] * wsh[q + 1];
            pl2 += pr_sh[q + 2][lane] * wsh[q + 2];
            pl3 += pr_sh[q + 3][lane] * wsh[q + 3];
        }
        float pooled = (pl0 + pl1) + (pl2 + pl3);
        float qv = qf[lane], rv = rf[lane];
        float sc = qv * rv * p1w[lane] + 5.0f * (rv - qv) * pooled * p2w[lane];
        float s = wred_sum(sc);
        if (lane == 0) out[b] = s + p1b[0] + 5.0f * p2b[0];
    }
}

extern "C" void kernel_launch(void* const* d_in, const int* in_sizes, int n_in,
                              void* d_out, int out_size, void* d_ws, size_t ws_size,
                              hipStream_t stream) {
    const int*   qry_id = (const int*)d_in[0];
    const int*   res_id = (const int*)d_in[1];
    const int*   path   = (const int*)d_in[2];
    const int*   mask   = (const int*)d_in[3];
    const float* img    = (const float*)d_in[4];
    const float* Ww     = (const float*)d_in[5];
    const float* Wb     = (const float*)d_in[6];
    const float* meta   = (const float*)d_in[7];
    const float* hw     = (const float*)d_in[8];
    const float* hb     = (const float*)d_in[9];
    const float* p1w    = (const float*)d_in[10];
    const float* p1b    = (const float*)d_in[11];
    const float* p2w    = (const float*)d_in[12];
    const float* p2b    = (const float*)d_in[13];

    float* out = (float*)d_out;

    hipLaunchKernelGGL(k_fused, dim3(BB), dim3(1024), 0, stream,
                       qry_id, res_id, path, mask, img, Ww, Wb, meta,
                       hw, hb, p1w, p1b, p2w, p2b, out);
}